// Round 1
// baseline (216.421 us; speedup 1.0000x reference)
//
#include <hip/hip_runtime.h>

#define NUM_LAYERS 32
#define HIDDEN 2048
#define RANK 64
#define BATCH 2048
#define HC 256              // h-chunk per block
#define NCH (HIDDEN / HC)   // 8 chunks
#define SB 8                // samples staged per inner batch

// Workspace layout:
//   [0, BATCH*RANK) floats             : proj accumulator (zeroed by K0)
//   then int counts[32], offsets[32], perm[BATCH]

__global__ __launch_bounds__(256)
void k_bucket_zero(const int* __restrict__ ids, float* __restrict__ proj,
                   int* __restrict__ counts, int* __restrict__ offsets,
                   int* __restrict__ perm)
{
    if (blockIdx.x == 0) {
        __shared__ int cnt[NUM_LAYERS];
        __shared__ int off[NUM_LAYERS];
        __shared__ int cur[NUM_LAYERS];
        const int t = threadIdx.x;
        if (t < NUM_LAYERS) cnt[t] = 0;
        __syncthreads();
        for (int i = t; i < BATCH; i += 256) atomicAdd(&cnt[ids[i]], 1);
        __syncthreads();
        if (t == 0) {
            int a = 0;
            for (int l = 0; l < NUM_LAYERS; ++l) { off[l] = a; a += cnt[l]; }
        }
        __syncthreads();
        if (t < NUM_LAYERS) { cur[t] = 0; counts[t] = cnt[t]; offsets[t] = off[t]; }
        __syncthreads();
        for (int i = t; i < BATCH; i += 256) {
            int l = ids[i];
            int p = off[l] + atomicAdd(&cur[l], 1);
            perm[p] = i;
        }
    } else {
        // blocks 1..64 zero proj: 131072 floats / 64 blocks = 2048 each
        const int base = (blockIdx.x - 1) * (BATCH * RANK / 64);
        for (int i = threadIdx.x; i < BATCH * RANK / 64; i += 256)
            proj[base + i] = 0.0f;
    }
}

// K1: proj[b,r] += sum_{h in chunk} v[l,h,r] * z[b,h]
// grid (NCH, NUM_LAYERS), 256 threads. Each thread group g (64 lanes) owns
// 64 h-values; lane r holds v[l, h, r] column segment in 64 VGPRs.
__global__ __launch_bounds__(256)
void k_proj(const float* __restrict__ z, const float* __restrict__ v,
            const int* __restrict__ counts, const int* __restrict__ offsets,
            const int* __restrict__ perm, float* __restrict__ proj)
{
    const int c = blockIdx.x, l = blockIdx.y;
    const int t = threadIdx.x;
    const int g = t >> 6, r = t & 63;
    const int hbase = c * HC + g * 64;

    // v slice into registers: wave-coalesced (lane r -> consecutive addrs)
    float vr[64];
    const float* vp = v + ((size_t)l * HIDDEN + hbase) * RANK + r;
    #pragma unroll
    for (int i = 0; i < 64; ++i) vr[i] = vp[(size_t)i * RANK];

    const int n = counts[l];
    const int o = offsets[l];

    __shared__ float zs[SB][HC];        // 8 KB staged z rows
    __shared__ float red[SB][4][RANK];  // 8 KB cross-group partials

    for (int s0 = 0; s0 < n; s0 += SB) {
        const int nb = (n - s0 < SB) ? (n - s0) : SB;
        __syncthreads();
        // stage z chunks, coalesced
        for (int idx = t; idx < nb * HC; idx += 256) {
            const int si = idx >> 8;       // HC == 256
            const int hh = idx & 255;
            const int b = perm[o + s0 + si];
            zs[si][hh] = z[(size_t)b * HIDDEN + c * HC + hh];
        }
        __syncthreads();

        float acc[SB];
        #pragma unroll
        for (int si = 0; si < SB; ++si) acc[si] = 0.0f;

        #pragma unroll
        for (int i4 = 0; i4 < 16; ++i4) {
            #pragma unroll
            for (int si = 0; si < SB; ++si) {
                // broadcast ds_read_b128 (all lanes same addr)
                const float4 zv = *(const float4*)&zs[si][g * 64 + i4 * 4];
                acc[si] += vr[i4 * 4 + 0] * zv.x + vr[i4 * 4 + 1] * zv.y
                         + vr[i4 * 4 + 2] * zv.z + vr[i4 * 4 + 3] * zv.w;
            }
        }

        #pragma unroll
        for (int si = 0; si < SB; ++si) red[si][g][r] = acc[si];
        __syncthreads();
        // reduce across 4 groups, one atomicAdd per (sample, r)
        for (int si = g; si < nb; si += 4) {
            const float s = red[si][0][r] + red[si][1][r]
                          + red[si][2][r] + red[si][3][r];
            const int b = perm[o + s0 + si];
            atomicAdd(&proj[b * RANK + r], s);
        }
    }
}

// K2: out[b,h] = z[b,h] + sum_r u[l,h,r] * proj[b,r]
// grid (NCH, NUM_LAYERS), 256 threads; thread t owns h = c*HC + t,
// holds u[l,h,:] (64 floats) in registers.
__global__ __launch_bounds__(256)
void k_delta(const float* __restrict__ z, const float* __restrict__ u,
             const int* __restrict__ counts, const int* __restrict__ offsets,
             const int* __restrict__ perm, const float* __restrict__ proj,
             float* __restrict__ out)
{
    const int c = blockIdx.x, l = blockIdx.y;
    const int t = threadIdx.x;
    const int h = c * HC + t;

    float ur[64];
    const float* up = u + ((size_t)l * HIDDEN + h) * RANK;
    #pragma unroll
    for (int i4 = 0; i4 < 16; ++i4) {
        const float4 tt = *(const float4*)&up[i4 * 4];
        ur[i4 * 4 + 0] = tt.x; ur[i4 * 4 + 1] = tt.y;
        ur[i4 * 4 + 2] = tt.z; ur[i4 * 4 + 3] = tt.w;
    }

    const int n = counts[l];
    const int o = offsets[l];

    __shared__ float ps[SB][RANK];  // 2 KB staged proj rows

    for (int s0 = 0; s0 < n; s0 += SB) {
        const int nb = (n - s0 < SB) ? (n - s0) : SB;
        __syncthreads();
        for (int idx = t; idx < nb * RANK; idx += 256) {
            const int si = idx >> 6;
            const int r = idx & 63;
            const int b = perm[o + s0 + si];
            ps[si][r] = proj[b * RANK + r];
        }
        __syncthreads();

        float acc[SB];
        #pragma unroll
        for (int si = 0; si < SB; ++si) acc[si] = 0.0f;

        #pragma unroll
        for (int i4 = 0; i4 < 16; ++i4) {
            #pragma unroll
            for (int si = 0; si < SB; ++si) {
                const float4 p4 = *(const float4*)&ps[si][i4 * 4];
                acc[si] += ur[i4 * 4 + 0] * p4.x + ur[i4 * 4 + 1] * p4.y
                         + ur[i4 * 4 + 2] * p4.z + ur[i4 * 4 + 3] * p4.w;
            }
        }

        for (int si = 0; si < nb; ++si) {
            const int b = perm[o + s0 + si];
            out[(size_t)b * HIDDEN + h] = z[(size_t)b * HIDDEN + h] + acc[si];
        }
    }
}

extern "C" void kernel_launch(void* const* d_in, const int* in_sizes, int n_in,
                              void* d_out, int out_size, void* d_ws, size_t ws_size,
                              hipStream_t stream)
{
    const float* z   = (const float*)d_in[0];
    const int*   ids = (const int*)d_in[1];
    const float* u   = (const float*)d_in[2];
    const float* v   = (const float*)d_in[3];
    float* out = (float*)d_out;

    float* proj   = (float*)d_ws;
    int* counts   = (int*)((char*)d_ws + (size_t)BATCH * RANK * sizeof(float));
    int* offsets  = counts + NUM_LAYERS;
    int* perm     = offsets + NUM_LAYERS;

    hipLaunchKernelGGL(k_bucket_zero, dim3(65), dim3(256), 0, stream,
                       ids, proj, counts, offsets, perm);
    hipLaunchKernelGGL(k_proj, dim3(NCH, NUM_LAYERS), dim3(256), 0, stream,
                       z, v, counts, offsets, perm, proj);
    hipLaunchKernelGGL(k_delta, dim3(NCH, NUM_LAYERS), dim3(256), 0, stream,
                       z, u, counts, offsets, perm, proj, out);
}

// Round 2
// 167.493 us; speedup vs baseline: 1.2921x; 1.2921x over previous
//
#include <hip/hip_runtime.h>

#define NUM_LAYERS 32
#define HIDDEN 2048
#define RANK 64
#define BATCH 2048
#define HC 256              // h-chunk per block
#define NCH (HIDDEN / HC)   // 8 chunks
#define CH 16               // samples per block
#define SC 8                // sample-chunks per layer (grid z)

// Workspace layout:
//   [0, BATCH*RANK) floats : proj accumulator (zeroed by K0)
//   then int counts[32], offsets[32], perm[BATCH]

__global__ __launch_bounds__(256)
void k_bucket_zero(const int* __restrict__ ids, float* __restrict__ proj,
                   int* __restrict__ counts, int* __restrict__ offsets,
                   int* __restrict__ perm)
{
    if (blockIdx.x == 0) {
        __shared__ int cnt[NUM_LAYERS];
        __shared__ int off[NUM_LAYERS];
        __shared__ int cur[NUM_LAYERS];
        const int t = threadIdx.x;
        if (t < NUM_LAYERS) cnt[t] = 0;
        __syncthreads();
        for (int i = t; i < BATCH; i += 256) atomicAdd(&cnt[ids[i]], 1);
        __syncthreads();
        if (t == 0) {
            int a = 0;
            for (int l = 0; l < NUM_LAYERS; ++l) { off[l] = a; a += cnt[l]; }
        }
        __syncthreads();
        if (t < NUM_LAYERS) { cur[t] = 0; counts[t] = cnt[t]; offsets[t] = off[t]; }
        __syncthreads();
        for (int i = t; i < BATCH; i += 256) {
            int l = ids[i];
            int p = off[l] + atomicAdd(&cur[l], 1);
            perm[p] = i;
        }
    } else {
        // blocks 1..64 zero proj: 131072 floats / 64 blocks = 2048 each
        const int base = (blockIdx.x - 1) * (BATCH * RANK / 64);
        for (int i = threadIdx.x; i < BATCH * RANK / 64; i += 256)
            proj[base + i] = 0.0f;
    }
}

// K1: proj[b,r] += sum_{h in chunk} v[l,h,r] * z[b,h]
// grid (NCH, NUM_LAYERS, SC), 256 threads. Group g (64 lanes) owns 64
// h-values; lane r holds v[l, hbase+i, r] in 64 VGPRs. Each block handles
// up to CH=16 samples of its layer.
__global__ __launch_bounds__(256)
void k_proj(const float* __restrict__ z, const float* __restrict__ v,
            const int* __restrict__ counts, const int* __restrict__ offsets,
            const int* __restrict__ perm, float* __restrict__ proj)
{
    const int c = blockIdx.x, l = blockIdx.y, sc = blockIdx.z;
    const int t = threadIdx.x;
    const int g = t >> 6, r = t & 63;
    const int hbase = c * HC + g * 64;

    // v slice into registers: wave-coalesced (lane r -> consecutive addrs)
    float vr[64];
    const float* vp = v + ((size_t)l * HIDDEN + hbase) * RANK + r;
    #pragma unroll
    for (int i = 0; i < 64; ++i) vr[i] = vp[(size_t)i * RANK];

    const int n = counts[l];
    const int o = offsets[l];

    __shared__ int   bidx[CH];
    __shared__ float zs[CH][HC];        // 16 KB staged z rows
    __shared__ float red[CH][4][RANK];  // 16 KB cross-group partials

    for (int base = sc * CH; base < n; base += SC * CH) {
        const int nb = (n - base < CH) ? (n - base) : CH;
        __syncthreads();
        if (t < nb) bidx[t] = perm[o + base + t];
        __syncthreads();
        // stage z chunks, coalesced
        for (int idx = t; idx < nb * HC; idx += 256) {
            const int si = idx >> 8;       // HC == 256
            const int hh = idx & 255;
            zs[si][hh] = z[(size_t)bidx[si] * HIDDEN + c * HC + hh];
        }
        __syncthreads();

        float acc[CH];
        #pragma unroll
        for (int si = 0; si < CH; ++si) acc[si] = 0.0f;

        #pragma unroll
        for (int i4 = 0; i4 < 16; ++i4) {
            #pragma unroll
            for (int si = 0; si < CH; ++si) {
                // broadcast ds_read_b128 (all lanes in a wave: same addr)
                const float4 zv = *(const float4*)&zs[si][g * 64 + i4 * 4];
                acc[si] += vr[i4 * 4 + 0] * zv.x + vr[i4 * 4 + 1] * zv.y
                         + vr[i4 * 4 + 2] * zv.z + vr[i4 * 4 + 3] * zv.w;
            }
        }

        #pragma unroll
        for (int si = 0; si < CH; ++si) red[si][g][r] = acc[si];
        __syncthreads();
        // reduce across 4 groups, one atomicAdd per (sample, r)
        for (int si = g; si < nb; si += 4) {
            const float s = red[si][0][r] + red[si][1][r]
                          + red[si][2][r] + red[si][3][r];
            atomicAdd(&proj[bidx[si] * RANK + r], s);
        }
    }
}

// K2: out[b,h] = z[b,h] + sum_r u[l,h,r] * proj[b,r]
// grid (NCH, NUM_LAYERS, SC), 256 threads; thread t owns h = c*HC + t,
// holds u[l,h,:] (64 floats) in registers; up to CH=16 samples per block.
__global__ __launch_bounds__(256)
void k_delta(const float* __restrict__ z, const float* __restrict__ u,
             const int* __restrict__ counts, const int* __restrict__ offsets,
             const int* __restrict__ perm, const float* __restrict__ proj,
             float* __restrict__ out)
{
    const int c = blockIdx.x, l = blockIdx.y, sc = blockIdx.z;
    const int t = threadIdx.x;
    const int h = c * HC + t;

    float ur[64];
    const float* up = u + ((size_t)l * HIDDEN + h) * RANK;
    #pragma unroll
    for (int i4 = 0; i4 < 16; ++i4) {
        const float4 tt = *(const float4*)&up[i4 * 4];
        ur[i4 * 4 + 0] = tt.x; ur[i4 * 4 + 1] = tt.y;
        ur[i4 * 4 + 2] = tt.z; ur[i4 * 4 + 3] = tt.w;
    }

    const int n = counts[l];
    const int o = offsets[l];

    __shared__ int   bidx[CH];
    __shared__ float ps[CH][RANK];  // 4 KB staged proj rows

    for (int base = sc * CH; base < n; base += SC * CH) {
        const int nb = (n - base < CH) ? (n - base) : CH;
        __syncthreads();
        if (t < nb) bidx[t] = perm[o + base + t];
        __syncthreads();
        for (int idx = t; idx < nb * RANK; idx += 256) {
            const int si = idx >> 6;
            const int r = idx & 63;
            ps[si][r] = proj[bidx[si] * RANK + r];
        }
        __syncthreads();

        float acc[CH];
        #pragma unroll
        for (int si = 0; si < CH; ++si) acc[si] = 0.0f;

        #pragma unroll
        for (int i4 = 0; i4 < 16; ++i4) {
            #pragma unroll
            for (int si = 0; si < CH; ++si) {
                const float4 p4 = *(const float4*)&ps[si][i4 * 4];
                acc[si] += ur[i4 * 4 + 0] * p4.x + ur[i4 * 4 + 1] * p4.y
                         + ur[i4 * 4 + 2] * p4.z + ur[i4 * 4 + 3] * p4.w;
            }
        }

        for (int si = 0; si < nb; ++si) {
            const int b = bidx[si];
            out[(size_t)b * HIDDEN + h] = z[(size_t)b * HIDDEN + h] + acc[si];
        }
    }
}

extern "C" void kernel_launch(void* const* d_in, const int* in_sizes, int n_in,
                              void* d_out, int out_size, void* d_ws, size_t ws_size,
                              hipStream_t stream)
{
    const float* z   = (const float*)d_in[0];
    const int*   ids = (const int*)d_in[1];
    const float* u   = (const float*)d_in[2];
    const float* v   = (const float*)d_in[3];
    float* out = (float*)d_out;

    float* proj   = (float*)d_ws;
    int* counts   = (int*)((char*)d_ws + (size_t)BATCH * RANK * sizeof(float));
    int* offsets  = counts + NUM_LAYERS;
    int* perm     = offsets + NUM_LAYERS;

    hipLaunchKernelGGL(k_bucket_zero, dim3(65), dim3(256), 0, stream,
                       ids, proj, counts, offsets, perm);
    hipLaunchKernelGGL(k_proj, dim3(NCH, NUM_LAYERS, SC), dim3(256), 0, stream,
                       z, v, counts, offsets, perm, proj);
    hipLaunchKernelGGL(k_delta, dim3(NCH, NUM_LAYERS, SC), dim3(256), 0, stream,
                       z, u, counts, offsets, perm, proj, out);
}